// Round 10
// baseline (147.107 us; speedup 1.0000x reference)
//
#include <hip/hip_runtime.h>
#include <hip/hip_bf16.h>

#define B_ 8
#define C_ 256
#define OC_ 128
#define L_ 4096
#define EPS_ 1e-5f
#define SPLITK 4
#define INV_L (1.0f / 4096.0f)

typedef unsigned short u16;
typedef __attribute__((ext_vector_type(4))) unsigned short u16x4;
typedef __attribute__((ext_vector_type(8))) unsigned short u16x8;
typedef __attribute__((ext_vector_type(4))) float f32x4;
typedef __attribute__((ext_vector_type(8))) short bf16x8;

__device__ inline u16 f2bf(float f) {
  union { __hip_bfloat16 h; u16 u; } v;
  v.h = __float2bfloat16(f);
  return v.u;
}
__device__ inline float bf2f(u16 u) {
  union { float f; unsigned u; } v;
  v.u = ((unsigned)u) << 16;
  return v.f;
}

__device__ inline void gload_lds16(const void* g, void* lds) {
  __builtin_amdgcn_global_load_lds(
      (const __attribute__((address_space(1))) unsigned int*)g,
      (__attribute__((address_space(3))) unsigned int*)lds, 16, 0, 0);
}

// blocks [0,2048): x -> Xb, XbT + spartial.  [2048,2056): P1=W_w@g_w (+P1T, w1).
// [2056,2064): P2T=(phi_w^T theta_w)^T (+rho, p2b, tbb).
__global__ __launch_bounds__(256) void k_cvt(
    const float* __restrict__ x, u16* __restrict__ Xb, u16* __restrict__ XbT,
    float* __restrict__ spartial,
    const float* __restrict__ W_w, const float* __restrict__ g_w,
    const float* __restrict__ g_b, const float* __restrict__ theta_w,
    const float* __restrict__ theta_b, const float* __restrict__ phi_w,
    const float* __restrict__ phi_b,
    u16* __restrict__ P1b, u16* __restrict__ P1Tb, u16* __restrict__ P2T,
    float* __restrict__ w1, float* __restrict__ rho, float* __restrict__ p2b,
    float* __restrict__ tbbg) {
  const int bid = blockIdx.x, tid = threadIdx.x;
  __shared__ u16 T[64][73];
  __shared__ float P[64][17];
  __shared__ float ww[32][OC_ + 1];
  __shared__ float gbs[OC_];
  __shared__ float tw[OC_][33];
  __shared__ float pbs[OC_], tbs[OC_];
  if (bid < 2048) {
    const int b = bid >> 8, ct = (bid >> 6) & 3, lt = bid & 63;
    const int c0 = ct * 64, l0 = lt * 64;
#pragma unroll
    for (int it = 0; it < 4; ++it) {
      int idx = it * 256 + tid;
      int row = idx >> 4;
      int col = (idx & 15) << 2;
      size_t gi = ((size_t)(b * C_ + c0 + row)) * L_ + l0 + col;
      float4 v = *(const float4*)(x + gi);
      u16 u0 = f2bf(v.x), u1_ = f2bf(v.y), u2 = f2bf(v.z), u3 = f2bf(v.w);
      u16x4 u = {u0, u1_, u2, u3};
      *(u16x4*)(Xb + gi) = u;
      T[row][col] = u0; T[row][col + 1] = u1_; T[row][col + 2] = u2; T[row][col + 3] = u3;
      P[row][idx & 15] = v.x + v.y + v.z + v.w;
    }
    __syncthreads();
    if (tid < 64) {
      float acc = 0.f;
#pragma unroll
      for (int j = 0; j < 16; j++) acc += P[tid][j];
      spartial[(size_t)lt * (B_ * C_) + b * C_ + c0 + tid] = acc;
    }
#pragma unroll
    for (int it = 0; it < 4; ++it) {
      int idx = it * 256 + tid;
      int lrow = idx >> 4;
      int ccol = (idx & 15) << 2;
      u16x4 u = {T[ccol][lrow], T[ccol + 1][lrow], T[ccol + 2][lrow], T[ccol + 3][lrow]};
      *(u16x4*)(XbT + ((size_t)b * L_ + l0 + lrow) * C_ + c0 + ccol) = u;
    }
  } else if (bid < 2056) {
    const int cbase = (bid - 2048) * 32;
    for (int i = tid; i < 32 * OC_; i += 256)
      ww[i >> 7][i & 127] = W_w[(size_t)(cbase + (i >> 7)) * OC_ + (i & 127)];
    if (tid < OC_) gbs[tid] = g_b[tid];
    __syncthreads();
    float acc[32] = {};
    for (int o = 0; o < OC_; o++) {
      float gv = g_w[(size_t)o * C_ + tid];
#pragma unroll
      for (int r = 0; r < 32; r++) acc[r] += ww[r][o] * gv;
    }
    u16 tr[32];
#pragma unroll
    for (int r = 0; r < 32; r++) {
      u16 h = f2bf(acc[r]);
      P1b[(size_t)(cbase + r) * C_ + tid] = h;
      tr[r] = h;
    }
#pragma unroll
    for (int k = 0; k < 4; k++) {
      u16x8 v;
#pragma unroll
      for (int j = 0; j < 8; j++) v[j] = tr[k * 8 + j];
      *(u16x8*)(P1Tb + (size_t)tid * C_ + cbase + k * 8) = v;
    }
    if (tid < 32) {
      float a = 0.f;
      for (int o = 0; o < OC_; o++) a += ww[tid][o] * gbs[o];
      w1[cbase + tid] = a;
    }
  } else {
    const int c2base = (bid - 2056) * 32;
    for (int i = tid; i < OC_ * 32; i += 256) {
      int op = i >> 5, r = i & 31;
      tw[op][r] = theta_w[(size_t)op * C_ + c2base + r];
    }
    if (tid < OC_) { pbs[tid] = phi_b[tid]; tbs[tid] = theta_b[tid]; }
    __syncthreads();
    float acc[32] = {};
    float ap2b = 0.f;
    for (int op = 0; op < OC_; op++) {
      float pv = phi_w[(size_t)op * C_ + tid];
#pragma unroll
      for (int r = 0; r < 32; r++) acc[r] += tw[op][r] * pv;
      ap2b += tbs[op] * pv;
    }
#pragma unroll
    for (int r = 0; r < 32; r++) P2T[(size_t)(c2base + r) * C_ + tid] = f2bf(acc[r]);
    if (bid == 2056) p2b[tid] = ap2b;
    if (tid < 32) {
      float a = 0.f;
      for (int op = 0; op < OC_; op++) a += pbs[op] * tw[op][tid];
      rho[c2base + tid] = a;
    }
    if (bid == 2056 && tid == 0) {
      float a = 0.f;
      for (int op = 0; op < OC_; op++) a += pbs[op] * tbs[op];
      tbbg[0] = a;
    }
  }
}

// S[b] = Xb Xb^T via MFMA bf16, split-K, 64x64 tiles, 2-phase dbuf.
// grid: (16, SPLITK, B) = 512 blocks, 256 thr.
__global__ __launch_bounds__(256) void k_xxt(const u16* __restrict__ Xb,
                                             float* __restrict__ Spart) {
  const int b = blockIdx.z, split = blockIdx.y;
  const int ti = blockIdx.x >> 2, tj = blockIdx.x & 3;
  __shared__ u16 lds[2][2][64 * 64];
  const int tid = threadIdx.x, lane = tid & 63;
  const int wid = tid >> 6, wr = wid >> 1, wc = wid & 1;
  const u16* Arows = Xb + ((size_t)b * C_ + ti * 64) * L_;
  const u16* Brows = Xb + ((size_t)b * C_ + tj * 64) * L_;
  const int k0 = split * (L_ / SPLITK);
  f32x4 acc[2][2] = {};

  auto STAGE = [&](int buf, int kt) {
#pragma unroll
    for (int ch = 0; ch < 2; ch++) {
      int d = ch * 4096 + tid * 16;
      int row = d >> 7;
      int kb = (d & 127) ^ ((row & 7) << 4);
      gload_lds16(Arows + (size_t)row * L_ + k0 + kt + (kb >> 1), (char*)lds[buf][0] + d);
      gload_lds16(Brows + (size_t)row * L_ + k0 + kt + (kb >> 1), (char*)lds[buf][1] + d);
    }
  };

  STAGE(0, 0);
  asm volatile("s_waitcnt vmcnt(0)" ::: "memory");
  __syncthreads();
  int cur = 0;
  for (int kt = 0; kt < L_ / SPLITK; kt += 64) {
    if (kt + 64 < L_ / SPLITK) STAGE(cur ^ 1, kt + 64);
#pragma unroll
    for (int kk = 0; kk < 2; kk++) {
      bf16x8 af[2], bfr[2];
#pragma unroll
      for (int m = 0; m < 2; m++) {
        int row = wr * 32 + m * 16 + (lane & 15);
        int kb = ((kk << 6) + ((lane >> 4) << 4)) ^ ((row & 7) << 4);
        af[m] = *(const bf16x8*)((const char*)lds[cur][0] + row * 128 + kb);
      }
#pragma unroll
      for (int n = 0; n < 2; n++) {
        int row = wc * 32 + n * 16 + (lane & 15);
        int kb = ((kk << 6) + ((lane >> 4) << 4)) ^ ((row & 7) << 4);
        bfr[n] = *(const bf16x8*)((const char*)lds[cur][1] + row * 128 + kb);
      }
#pragma unroll
      for (int m = 0; m < 2; m++)
#pragma unroll
        for (int n = 0; n < 2; n++)
          acc[m][n] = __builtin_amdgcn_mfma_f32_16x16x32_bf16(af[m], bfr[n], acc[m][n], 0, 0, 0);
    }
    asm volatile("s_waitcnt vmcnt(0)" ::: "memory");
    __syncthreads();
    cur ^= 1;
  }
  float* Sp = Spart + ((size_t)split * B_ + b) * C_ * C_;
#pragma unroll
  for (int m = 0; m < 2; m++)
#pragma unroll
    for (int n = 0; n < 2; n++) {
      int r0 = ti * 64 + wr * 32 + m * 16 + ((lane >> 4) << 2);
      int c0 = tj * 64 + wc * 32 + n * 16 + (lane & 15);
#pragma unroll
      for (int r = 0; r < 4; r++)
        Sp[(size_t)(r0 + r) * C_ + c0] = acc[m][n][r];
    }
}

// Q[b] = (1/L)(P1 S P2 + w1 v1^T + u1 rho^T) + w1 rho^T, via two chained MFMA GEMMs.
// Also qv (js==0), qspart. grid: (4 js, B), 256 thr.
__global__ __launch_bounds__(256) void k_qgen(
    const float* __restrict__ Spart, const float* __restrict__ spartial,
    const u16* __restrict__ P1b, const u16* __restrict__ P1Tb,
    const u16* __restrict__ P2T,
    const float* __restrict__ w1g, const float* __restrict__ rho,
    const float* __restrict__ p2b, const float* __restrict__ tbbg,
    const float* __restrict__ W_b,
    u16* __restrict__ Qb, float* __restrict__ qv, float* __restrict__ qspart) {
  const int js = blockIdx.x, b = blockIdx.y;
  const int tid = threadIdx.x, lane = tid & 63, wid = tid >> 6;
  __shared__ u16 Abuf[256 * 64];   // 32KB, swizzled
  __shared__ u16 Bbuf[64 * 64];    // 8KB, swizzled
  __shared__ u16 Tt[64][264];      // T transposed, bf16, padded
  __shared__ float s_l[C_], u1_l[C_], z_l[C_], p2b_l[C_], w1_l[C_];
  __shared__ float v1_l[64], red[4];
  // s, small vectors
  {
    float a = 0.f;
    for (int lt = 0; lt < 64; lt++) a += spartial[(size_t)lt * (B_ * C_) + b * C_ + tid];
    s_l[tid] = a;
    p2b_l[tid] = p2b[tid];
    w1_l[tid] = w1g[tid];
  }
  // sp2b (needs only own-lane s_l/p2b_l)
  float part = s_l[tid] * p2b_l[tid];
#pragma unroll
  for (int off = 1; off < 64; off <<= 1) part += __shfl_xor(part, off, 64);
  if (lane == 0) red[wid] = part;
  __syncthreads();
  const float sp2b = red[0] + red[1] + red[2] + red[3];
  // GEMM1: T = S @ P2T_js  (A: 256xk staged bf16 from 4-split Spart; B: P2T rows)
  f32x4 acc[4][4] = {};
  for (int kt = 0; kt < C_; kt += 64) {
    __syncthreads();
    {
      const int jr = (tid & 15) * 4;
      const int rb = tid >> 4;
#pragma unroll 4
      for (int pass = 0; pass < 16; pass++) {
        int row = pass * 16 + rb;
        float4 a0 = {0.f, 0.f, 0.f, 0.f};
#pragma unroll
        for (int sp = 0; sp < SPLITK; sp++) {
          float4 v = *(const float4*)(Spart + ((size_t)sp * B_ + b) * (C_ * C_) +
                                      (size_t)row * C_ + kt + jr);
          a0.x += v.x; a0.y += v.y; a0.z += v.z; a0.w += v.w;
        }
        u16x4 h = {f2bf(a0.x), f2bf(a0.y), f2bf(a0.z), f2bf(a0.w)};
        int byte = (jr * 2) ^ ((row & 7) << 4);
        *(u16x4*)((char*)Abuf + row * 128 + byte) = h;
      }
#pragma unroll
      for (int ch = 0; ch < 2; ch++) {
        int d = ch * 4096 + tid * 16;
        int row = d >> 7;
        int kb = (d & 127) ^ ((row & 7) << 4);
        gload_lds16(P2T + (size_t)(js * 64 + row) * C_ + kt + (kb >> 1), (char*)Bbuf + d);
      }
    }
    asm volatile("s_waitcnt vmcnt(0)" ::: "memory");
    __syncthreads();
#pragma unroll
    for (int kk = 0; kk < 2; kk++) {
      bf16x8 af[4], bfr[4];
#pragma unroll
      for (int m = 0; m < 4; m++) {
        int row = wid * 64 + m * 16 + (lane & 15);
        int kb = ((kk << 6) + ((lane >> 4) << 4)) ^ ((row & 7) << 4);
        af[m] = *(const bf16x8*)((const char*)Abuf + row * 128 + kb);
      }
#pragma unroll
      for (int n = 0; n < 4; n++) {
        int row = n * 16 + (lane & 15);
        int kb = ((kk << 6) + ((lane >> 4) << 4)) ^ ((row & 7) << 4);
        bfr[n] = *(const bf16x8*)((const char*)Bbuf + row * 128 + kb);
      }
#pragma unroll
      for (int m = 0; m < 4; m++)
#pragma unroll
        for (int n = 0; n < 4; n++)
          acc[m][n] = __builtin_amdgcn_mfma_f32_16x16x32_bf16(af[m], bfr[n], acc[m][n], 0, 0, 0);
    }
  }
  // write Tt[j][t] (bf16)
#pragma unroll
  for (int m = 0; m < 4; m++)
#pragma unroll
    for (int n = 0; n < 4; n++) {
      int j = n * 16 + (lane & 15);
      int t0 = wid * 64 + m * 16 + ((lane >> 4) << 2);
      u16x4 h = {f2bf(acc[m][n][0]), f2bf(acc[m][n][1]), f2bf(acc[m][n][2]), f2bf(acc[m][n][3])};
      *(u16x4*)((char*)&Tt[0][0] + j * 528 + t0 * 2) = h;
    }
  // aux: u1 = P1 s (via P1T coalesced), v1 = P2T_js s; z (js==0)
  {
    float a = 0.f;
    for (int cp = 0; cp < C_; cp++) a += bf2f(P1Tb[(size_t)cp * C_ + tid]) * s_l[cp];
    u1_l[tid] = a;
  }
  if (tid < 64) {
    float a = 0.f;
    const u16x8* pr = (const u16x8*)(P2T + (size_t)(js * 64 + tid) * C_);
    for (int i = 0; i < 32; i++) {
      u16x8 v = pr[i];
#pragma unroll
      for (int k = 0; k < 8; k++) a += bf2f(v[k]) * s_l[i * 8 + k];
    }
    v1_l[tid] = a;
  }
  if (js == 0) {
    float a = 0.f;
    for (int sp = 0; sp < SPLITK; sp++)
      for (int cp = 0; cp < C_; cp++)
        a += Spart[((size_t)sp * B_ + b) * (C_ * C_) + (size_t)cp * C_ + tid] * p2b_l[cp];
    z_l[tid] = a;
  }
  __syncthreads();
  if (js == 0) {
    float qq = 0.f;
    for (int cp = 0; cp < C_; cp++) qq += bf2f(P1Tb[(size_t)cp * C_ + tid]) * z_l[cp];
    float tbb = tbbg[0];
    float w1c = w1_l[tid];
    qv[b * C_ + tid] = INV_L * (qq + w1c * sp2b + u1_l[tid] * tbb) + w1c * tbb + W_b[tid];
  }
  // GEMM2: Q_slice = P1 @ T   (A: P1b gload; B: Tt in LDS)
  f32x4 acc2[4][4] = {};
  for (int kt = 0; kt < C_; kt += 64) {
    __syncthreads();
#pragma unroll
    for (int ch = 0; ch < 8; ch++) {
      int d = ch * 4096 + tid * 16;
      int row = d >> 7;
      int kb = (d & 127) ^ ((row & 7) << 4);
      gload_lds16(P1b + (size_t)row * C_ + kt + (kb >> 1), (char*)Abuf + d);
    }
    asm volatile("s_waitcnt vmcnt(0)" ::: "memory");
    __syncthreads();
#pragma unroll
    for (int kk = 0; kk < 2; kk++) {
      bf16x8 af[4], bfr[4];
#pragma unroll
      for (int m = 0; m < 4; m++) {
        int row = wid * 64 + m * 16 + (lane & 15);
        int kb = ((kk << 6) + ((lane >> 4) << 4)) ^ ((row & 7) << 4);
        af[m] = *(const bf16x8*)((const char*)Abuf + row * 128 + kb);
      }
#pragma unroll
      for (int n = 0; n < 4; n++) {
        int j = n * 16 + (lane & 15);
        int ke = kt + kk * 32 + ((lane >> 4) << 3);
        bfr[n] = *(const bf16x8*)((const char*)&Tt[0][0] + j * 528 + ke * 2);
      }
#pragma unroll
      for (int m = 0; m < 4; m++)
#pragma unroll
        for (int n = 0; n < 4; n++)
          acc2[m][n] = __builtin_amdgcn_mfma_f32_16x16x32_bf16(af[m], bfr[n], acc2[m][n], 0, 0, 0);
    }
  }
  // epilogue: rank-1 terms, write Qb, qs partials
  float rho_j[4], v1_j[4];
#pragma unroll
  for (int n = 0; n < 4; n++) {
    rho_j[n] = rho[js * 64 + n * 16 + (lane & 15)];
    v1_j[n] = v1_l[n * 16 + (lane & 15)];
  }
#pragma unroll
  for (int m = 0; m < 4; m++) {
    int c0 = wid * 64 + m * 16 + ((lane >> 4) << 2);
    float qsp_acc[4] = {};
#pragma unroll
    for (int n = 0; n < 4; n++) {
      int jg = js * 64 + n * 16 + (lane & 15);
      float sj = s_l[jg];
#pragma unroll
      for (int r = 0; r < 4; r++) {
        int c = c0 + r;
        float q = INV_L * acc2[m][n][r] + w1_l[c] * (INV_L * v1_j[n] + rho_j[n]) +
                  INV_L * u1_l[c] * rho_j[n];
        Qb[((size_t)b * C_ + c) * C_ + jg] = f2bf(q);
        qsp_acc[r] += q * sj;
      }
    }
#pragma unroll
    for (int r = 0; r < 4; r++) {
      float v = qsp_acc[r];
      v += __shfl_xor(v, 1, 64);
      v += __shfl_xor(v, 2, 64);
      v += __shfl_xor(v, 4, 64);
      v += __shfl_xor(v, 8, 64);
      if ((lane & 15) == 0)
        qspart[((size_t)js * B_ + b) * C_ + c0 + r] = v;
    }
  }
}

// e2 partials via MFMA; B-side staged bf16 from 4-split Spart.
// grid: (4 ks, 4 (chs*2+ct), B) = 128 blocks.
__global__ __launch_bounds__(256) void k_ystat(const u16* __restrict__ Qb,
                                               const float* __restrict__ Spart,
                                               float* __restrict__ e2part) {
  const int b = blockIdx.z;
  const int chs = blockIdx.y >> 1, ct = blockIdx.y & 1;
  const int ks = blockIdx.x;
  __shared__ u16 lds[2 * 128 * 64];
  __shared__ float e2s[128][2];
  const int tid = threadIdx.x, lane = tid & 63;
  const int wid = tid >> 6, wr = wid >> 1, wc = wid & 1;
  const u16* Abase = Qb + ((size_t)b * C_ + ct * 128) * C_;
  const int k0 = ks * 64;
  f32x4 acc[4][4] = {};
#pragma unroll
  for (int ch = 0; ch < 4; ch++) {
    int d = ch * 4096 + tid * 16;
    int row = d >> 7;
    int kb = (d & 127) ^ ((row & 7) << 4);
    gload_lds16(Abase + (size_t)row * C_ + k0 + (kb >> 1), (char*)lds + d);
  }
  {
    const int jr = (tid & 15) * 4;
    const int rb = tid >> 4;
#pragma unroll 4
    for (int pass = 0; pass < 8; pass++) {
      int row = pass * 16 + rb;
      float4 a0 = {0.f, 0.f, 0.f, 0.f};
#pragma unroll
      for (int sp = 0; sp < SPLITK; sp++) {
        float4 v = *(const float4*)(Spart + ((size_t)sp * B_ + b) * (C_ * C_) +
                                    (size_t)(chs * 128 + row) * C_ + k0 + jr);
        a0.x += v.x; a0.y += v.y; a0.z += v.z; a0.w += v.w;
      }
      u16x4 h = {f2bf(a0.x), f2bf(a0.y), f2bf(a0.z), f2bf(a0.w)};
      int byte = (jr * 2) ^ ((row & 7) << 4);
      *(u16x4*)((char*)lds + 16384 + row * 128 + byte) = h;
    }
  }
  asm volatile("s_waitcnt vmcnt(0)" ::: "memory");
  __syncthreads();
#pragma unroll
  for (int kk = 0; kk < 2; kk++) {
    bf16x8 af[4], bfr[4];
#pragma unroll
    for (int m = 0; m < 4; m++) {
      int row = wr * 64 + m * 16 + (lane & 15);
      int kb = ((kk << 6) + ((lane >> 4) << 4)) ^ ((row & 7) << 4);
      af[m] = *(const bf16x8*)((const char*)lds + row * 128 + kb);
    }
#pragma unroll
    for (int n = 0; n < 4; n++) {
      int row = wc * 64 + n * 16 + (lane & 15);
      int kb = ((kk << 6) + ((lane >> 4) << 4)) ^ ((row & 7) << 4);
      bfr[n] = *(const bf16x8*)((const char*)lds + 16384 + row * 128 + kb);
    }
#pragma unroll
    for (int m = 0; m < 4; m++)
#pragma unroll
      for (int n = 0; n < 4; n++)
        acc[m][n] = __builtin_amdgcn_mfma_f32_16x16x32_bf16(af[m], bfr[n], acc[m][n], 0, 0, 0);
  }
  float e2a[4][4];
#pragma unroll
  for (int m = 0; m < 4; m++)
#pragma unroll
    for (int r = 0; r < 4; r++) e2a[m][r] = 0.f;
#pragma unroll
  for (int m = 0; m < 4; m++)
#pragma unroll
    for (int n = 0; n < 4; n++) {
      int ch = chs * 128 + wc * 64 + n * 16 + (lane & 15);
#pragma unroll
      for (int r = 0; r < 4; r++) {
        int c_loc = wr * 64 + m * 16 + ((lane >> 4) << 2) + r;
        float q2 = bf2f(Qb[((size_t)b * C_ + ct * 128 + c_loc) * C_ + ch]);
        e2a[m][r] += acc[m][n][r] * q2;
      }
    }
#pragma unroll
  for (int m = 0; m < 4; m++)
#pragma unroll
    for (int r = 0; r < 4; r++) {
      float v = e2a[m][r];
      v += __shfl_xor(v, 1, 64);
      v += __shfl_xor(v, 2, 64);
      v += __shfl_xor(v, 4, 64);
      v += __shfl_xor(v, 8, 64);
      if ((lane & 15) == 0) {
        int c_loc = wr * 64 + m * 16 + ((lane >> 4) << 2) + r;
        e2s[c_loc][wc] = v;
      }
    }
  __syncthreads();
  if (tid < 128)
    e2part[(((size_t)chs * 4 + ks) * B_ + b) * C_ + ct * 128 + tid] =
        e2s[tid][0] + e2s[tid][1];
}

// BN finalize (prologue) + out = (gsc*Qb + I) @ Xb + qp.  A reg-staged, B gload, dbuf.
// grid: (L/128, C/128, B) = 512 blocks, 256 thr.
__global__ __launch_bounds__(256) void k_out(const u16* __restrict__ Qb,
                                             const float* __restrict__ qv,
                                             const float* __restrict__ qspart,
                                             const float* __restrict__ e2part,
                                             const float* __restrict__ gamma,
                                             const float* __restrict__ beta,
                                             const u16* __restrict__ XbT,
                                             float* __restrict__ out) {
  const int b = blockIdx.z, ct = blockIdx.y, lt = blockIdx.x;
  __shared__ u16 Albs[2][128 * 64];
  __shared__ u16 Blbs[2][128 * 64];
  __shared__ float gsc_s[128], qp_s[128];
  const int tid = threadIdx.x, lane = tid & 63;
  const int wid = tid >> 6, wr = wid >> 1, wc = wid & 1;
  if (tid < 128) {
    int c = ct * 128 + tid;
    float m_ = 0.f, e_ = 0.f;
#pragma unroll
    for (int bb = 0; bb < B_; bb++) {
      float qsv = 0.f;
#pragma unroll
      for (int jss = 0; jss < 4; jss++) qsv += qspart[((size_t)jss * B_ + bb) * C_ + c];
      float qvv = qv[bb * C_ + c];
      m_ += qsv + (float)L_ * qvv;
      float e2 = 0.f;
#pragma unroll
      for (int sl = 0; sl < 8; sl++) e2 += e2part[((size_t)sl * B_ + bb) * C_ + c];
      e_ += e2 + 2.f * qvv * qsv + (float)L_ * qvv * qvv;
    }
    const float inv_n = 1.f / (float)(B_ * L_);
    m_ *= inv_n;
    e_ *= inv_n;
    float var = e_ - m_ * m_;
    float g = gamma[c] * rsqrtf(var + EPS_);
    gsc_s[tid] = g;
    qp_s[tid] = g * (qv[b * C_ + c] - m_) + beta[c];
  }
  __syncthreads();
  const u16* Bbase = XbT + ((size_t)b * L_ + lt * 128) * C_;
  f32x4 acc[4][4] = {};
  u16x4 regs[8];
  const int jr = (tid & 15) * 4;
  const int rb = tid >> 4;
  auto LOADA = [&](int k0) {
#pragma unroll
    for (int pass = 0; pass < 8; pass++) {
      int row = pass * 16 + rb;
      regs[pass] = *(const u16x4*)(Qb + ((size_t)b * C_ + ct * 128 + row) * C_ + k0 + jr);
    }
  };
  auto WRITEA = [&](int buf, int k0) {
#pragma unroll
    for (int pass = 0; pass < 8; pass++) {
      int row = pass * 16 + rb;
      float g = gsc_s[row];
      int c = ct * 128 + row;
      u16x4 h;
#pragma unroll
      for (int i = 0; i < 4; i++) {
        float a = g * bf2f(regs[pass][i]);
        if (k0 + jr + i == c) a += 1.f;
        h[i] = f2bf(a);
      }
      int byte = (jr * 2) ^ ((row & 7) << 4);
      *(u16x4*)((char*)Albs[buf] + row * 128 + byte) = h;
    }
  };
  auto STAGEB = [&](int buf, int k0) {
#pragma unroll
    for (int ch = 0; ch < 4; ch++) {
      int d = ch * 4096 + tid * 16;
      int row = d >> 7;
      int kb = (d & 127) ^ ((row & 7) << 4);
      gload_lds16(Bbase + (size_t)row * C_ + k0 + (kb >> 1), (char*)Blbs[buf] + d);
    }
  };
  LOADA(0);
  STAGEB(0, 0);
  asm volatile("s_waitcnt vmcnt(0)" ::: "memory");
  WRITEA(0, 0);
  __syncthreads();
  int cur = 0;
  for (int k0 = 0; k0 < C_; k0 += 64) {
    bool hasNext = (k0 + 64 < C_);
    if (hasNext) {
      STAGEB(cur ^ 1, k0 + 64);
      LOADA(k0 + 64);
    }
#pragma unroll
    for (int kk = 0; kk < 2; kk++) {
      bf16x8 af[4], bfr[4];
#pragma unroll
      for (int m = 0; m < 4; m++) {
        int row = wr * 64 + m * 16 + (lane & 15);
        int kb = ((kk << 6) + ((lane >> 4) << 4)) ^ ((row & 7) << 4);
        af[m] = *(const bf16x8*)((const char*)Albs[cur] + (row & 127) * 128 + kb);
      }
#pragma unroll
      for (int n = 0; n < 4; n++) {
        int row = wc * 64 + n * 16 + (lane & 15);
        int kb = ((kk << 6) + ((lane >> 4) << 4)) ^ ((row & 7) << 4);
        bfr[n] = *(const bf16x8*)((const char*)Blbs[cur] + row * 128 + kb);
      }
#pragma unroll
      for (int m = 0; m < 4; m++)
#pragma unroll
        for (int n = 0; n < 4; n++)
          acc[m][n] = __builtin_amdgcn_mfma_f32_16x16x32_bf16(af[m], bfr[n], acc[m][n], 0, 0, 0);
    }
    if (hasNext) {
      asm volatile("s_waitcnt vmcnt(0)" ::: "memory");
      WRITEA(cur ^ 1, k0 + 64);
    }
    __syncthreads();
    cur ^= 1;
  }
#pragma unroll
  for (int m = 0; m < 4; m++)
#pragma unroll
    for (int n = 0; n < 4; n++) {
      int cl = wr * 64 + m * 16 + ((lane >> 4) << 2);
      int c = ct * 128 + cl;
      int l = lt * 128 + wc * 64 + n * 16 + (lane & 15);
#pragma unroll
      for (int r = 0; r < 4; r++) {
        size_t gi = ((size_t)b * C_ + c + r) * L_ + l;
        out[gi] = acc[m][n][r] + qp_s[cl + r];
      }
    }
}

extern "C" void kernel_launch(void* const* d_in, const int* in_sizes, int n_in,
                              void* d_out, int out_size, void* d_ws, size_t ws_size,
                              hipStream_t stream) {
  const float* x       = (const float*)d_in[0];
  const float* g_w     = (const float*)d_in[1];
  const float* g_b     = (const float*)d_in[2];
  const float* theta_w = (const float*)d_in[3];
  const float* theta_b = (const float*)d_in[4];
  const float* phi_w   = (const float*)d_in[5];
  const float* phi_b   = (const float*)d_in[6];
  const float* W_w     = (const float*)d_in[7];
  const float* W_b     = (const float*)d_in[8];
  const float* gamma   = (const float*)d_in[9];
  const float* beta    = (const float*)d_in[10];
  float* out = (float*)d_out;

  float* ws = (float*)d_ws;
  size_t off = 0;
  float* Spart    = ws + off; off += (size_t)SPLITK * B_ * C_ * C_;  // 8MB
  float* spartial = ws + off; off += (size_t)B_ * C_ * 64;
  float* qv       = ws + off; off += B_ * C_;
  float* qspart   = ws + off; off += 4 * B_ * C_;
  float* e2part   = ws + off; off += 8 * B_ * C_;
  float* w1       = ws + off; off += C_;
  float* rho      = ws + off; off += C_;
  float* p2b      = ws + off; off += C_;
  float* tbbg     = ws + off; off += 64;
  u16* P1b  = (u16*)(ws + off); off += C_ * C_ / 2;
  u16* P1Tb = (u16*)(ws + off); off += C_ * C_ / 2;
  u16* P2T  = (u16*)(ws + off); off += C_ * C_ / 2;
  u16* Qb   = (u16*)(ws + off); off += (size_t)B_ * C_ * C_ / 2;
  u16* Xb   = (u16*)(ws + off); off += (size_t)B_ * C_ * L_ / 2;
  u16* XbT  = (u16*)(ws + off); off += (size_t)B_ * C_ * L_ / 2;

  k_cvt<<<2064, 256, 0, stream>>>(x, Xb, XbT, spartial, W_w, g_w, g_b, theta_w,
                                  theta_b, phi_w, phi_b, P1b, P1Tb, P2T, w1, rho,
                                  p2b, tbbg);
  k_xxt<<<dim3(16, SPLITK, B_), 256, 0, stream>>>(Xb, Spart);
  k_qgen<<<dim3(4, B_), 256, 0, stream>>>(Spart, spartial, P1b, P1Tb, P2T, w1,
                                          rho, p2b, tbbg, W_b, Qb, qv, qspart);
  k_ystat<<<dim3(4, 4, B_), 256, 0, stream>>>(Qb, Spart, e2part);
  k_out<<<dim3(L_ / 128, C_ / 128, B_), 256, 0, stream>>>(
      Qb, qv, qspart, e2part, gamma, beta, XbT, out);
}

// Round 11
// 121.018 us; speedup vs baseline: 1.2156x; 1.2156x over previous
//
#include <hip/hip_runtime.h>
#include <hip/hip_bf16.h>

#define B_ 8
#define C_ 256
#define OC_ 128
#define L_ 4096
#define EPS_ 1e-5f
#define SPLITK 4

typedef unsigned short u16;
typedef __attribute__((ext_vector_type(4))) unsigned short u16x4;
typedef __attribute__((ext_vector_type(8))) unsigned short u16x8;
typedef __attribute__((ext_vector_type(4))) float f32x4;
typedef __attribute__((ext_vector_type(8))) short bf16x8;

__device__ inline u16 f2bf(float f) {
  union { __hip_bfloat16 h; u16 u; } v;
  v.h = __float2bfloat16(f);
  return v.u;
}
__device__ inline float bf2f(u16 u) {
  union { float f; unsigned u; } v;
  v.u = ((unsigned)u) << 16;
  return v.f;
}

__device__ inline void gload_lds16(const void* g, void* lds) {
  __builtin_amdgcn_global_load_lds(
      (const __attribute__((address_space(1))) unsigned int*)g,
      (__attribute__((address_space(3))) unsigned int*)lds, 16, 0, 0);
}

// x -> Xb[b][c][l], XbT[b][l][c] (bf16), + partial row sums spartial[ltile][b*C+c]
__global__ __launch_bounds__(256) void k_cvt(const float* __restrict__ x,
                                             u16* __restrict__ Xb,
                                             u16* __restrict__ XbT,
                                             float* __restrict__ spartial) {
  __shared__ u16 T[64][73];
  __shared__ float P[64][17];
  const int b = blockIdx.z, c0 = blockIdx.y * 64, l0 = blockIdx.x * 64;
  const int tid = threadIdx.x;
#pragma unroll
  for (int it = 0; it < 4; ++it) {
    int idx = it * 256 + tid;
    int row = idx >> 4;
    int col = (idx & 15) << 2;
    size_t gi = ((size_t)(b * C_ + c0 + row)) * L_ + l0 + col;
    float4 v = *(const float4*)(x + gi);
    u16 u0 = f2bf(v.x), u1 = f2bf(v.y), u2 = f2bf(v.z), u3 = f2bf(v.w);
    u16x4 u = {u0, u1, u2, u3};
    *(u16x4*)(Xb + gi) = u;
    T[row][col] = u0; T[row][col + 1] = u1; T[row][col + 2] = u2; T[row][col + 3] = u3;
    P[row][idx & 15] = v.x + v.y + v.z + v.w;
  }
  __syncthreads();
  if (tid < 64) {
    float acc = 0.f;
#pragma unroll
    for (int j = 0; j < 16; j++) acc += P[tid][j];
    spartial[(size_t)blockIdx.x * (B_ * C_) + b * C_ + c0 + tid] = acc;
  }
#pragma unroll
  for (int it = 0; it < 4; ++it) {
    int idx = it * 256 + tid;
    int lrow = idx >> 4;
    int ccol = (idx & 15) << 2;
    u16x4 u = {T[ccol][lrow], T[ccol + 1][lrow], T[ccol + 2][lrow], T[ccol + 3][lrow]};
    *(u16x4*)(XbT + ((size_t)b * L_ + l0 + lrow) * C_ + c0 + ccol) = u;
  }
}

// S[b] = Xb Xb^T via MFMA bf16, split-K, 64x64 tiles, 2-phase dbuf.
// grid: (16, SPLITK, B) = 512 blocks, 256 thr.
__global__ __launch_bounds__(256) void k_xxt(const u16* __restrict__ Xb,
                                             float* __restrict__ Spart) {
  const int b = blockIdx.z, split = blockIdx.y;
  const int ti = blockIdx.x >> 2, tj = blockIdx.x & 3;
  __shared__ u16 lds[2][2][64 * 64];
  const int tid = threadIdx.x, lane = tid & 63;
  const int wid = tid >> 6, wr = wid >> 1, wc = wid & 1;
  const u16* Arows = Xb + ((size_t)b * C_ + ti * 64) * L_;
  const u16* Brows = Xb + ((size_t)b * C_ + tj * 64) * L_;
  const int k0 = split * (L_ / SPLITK);
  f32x4 acc[2][2] = {};

  auto STAGE = [&](int buf, int kt) {
#pragma unroll
    for (int ch = 0; ch < 2; ch++) {
      int d = ch * 4096 + tid * 16;
      int row = d >> 7;
      int kb = (d & 127) ^ ((row & 7) << 4);
      gload_lds16(Arows + (size_t)row * L_ + k0 + kt + (kb >> 1), (char*)lds[buf][0] + d);
      gload_lds16(Brows + (size_t)row * L_ + k0 + kt + (kb >> 1), (char*)lds[buf][1] + d);
    }
  };

  STAGE(0, 0);
  asm volatile("s_waitcnt vmcnt(0)" ::: "memory");
  __syncthreads();
  int cur = 0;
  for (int kt = 0; kt < L_ / SPLITK; kt += 64) {
    if (kt + 64 < L_ / SPLITK) STAGE(cur ^ 1, kt + 64);
#pragma unroll
    for (int kk = 0; kk < 2; kk++) {
      bf16x8 af[2], bfr[2];
#pragma unroll
      for (int m = 0; m < 2; m++) {
        int row = wr * 32 + m * 16 + (lane & 15);
        int kb = ((kk << 6) + ((lane >> 4) << 4)) ^ ((row & 7) << 4);
        af[m] = *(const bf16x8*)((const char*)lds[cur][0] + row * 128 + kb);
      }
#pragma unroll
      for (int n = 0; n < 2; n++) {
        int row = wc * 32 + n * 16 + (lane & 15);
        int kb = ((kk << 6) + ((lane >> 4) << 4)) ^ ((row & 7) << 4);
        bfr[n] = *(const bf16x8*)((const char*)lds[cur][1] + row * 128 + kb);
      }
#pragma unroll
      for (int m = 0; m < 2; m++)
#pragma unroll
        for (int n = 0; n < 2; n++)
          acc[m][n] = __builtin_amdgcn_mfma_f32_16x16x32_bf16(af[m], bfr[n], acc[m][n], 0, 0, 0);
    }
    asm volatile("s_waitcnt vmcnt(0)" ::: "memory");
    __syncthreads();
    cur ^= 1;
  }
  float* Sp = Spart + ((size_t)split * B_ + b) * C_ * C_;
#pragma unroll
  for (int m = 0; m < 2; m++)
#pragma unroll
    for (int n = 0; n < 2; n++) {
      int r0 = ti * 64 + wr * 32 + m * 16 + ((lane >> 4) << 2);
      int c0 = tj * 64 + wc * 32 + n * 16 + (lane & 15);
#pragma unroll
      for (int r = 0; r < 4; r++)
        Sp[(size_t)(r0 + r) * C_ + c0] = acc[m][n][r];
    }
}

// blocks <2048: S (+ Sb bf16); 2048-2055: s; 2056-2071: gwT = g_w^T
__global__ __launch_bounds__(256) void k_sreduce(const float* __restrict__ Spart,
                                                 const float* __restrict__ spartial,
                                                 const float* __restrict__ g_w,
                                                 float* __restrict__ S,
                                                 u16* __restrict__ Sb,
                                                 float* __restrict__ s,
                                                 float* __restrict__ gwT) {
  const int bid = blockIdx.x, tid = threadIdx.x;
  if (bid < (B_ * C_ * C_) / 256) {
    size_t idx = (size_t)bid * 256 + tid;
    float acc = 0.f;
    for (int sp = 0; sp < SPLITK; sp++) acc += Spart[(size_t)sp * B_ * C_ * C_ + idx];
    S[idx] = acc;
    Sb[idx] = f2bf(acc);
  } else if (bid < (B_ * C_ * C_) / 256 + (B_ * C_) / 256) {
    int idx2 = (bid - (B_ * C_ * C_) / 256) * 256 + tid;
    float acc = 0.f;
#pragma unroll 8
    for (int i = 0; i < 64; i++) acc += spartial[(size_t)i * (B_ * C_) + idx2];
    s[idx2] = acc;
  } else {
    int t = bid - ((B_ * C_ * C_) / 256 + (B_ * C_) / 256);
    int o = t * 8 + (tid & 7);
    int cbase = (tid >> 3) * 8;
#pragma unroll
    for (int k = 0; k < 8; k++) {
      int c = cbase + k;
      gwT[c * OC_ + o] = g_w[o * C_ + c];
    }
  }
}

// MT[b][o][op] for a 4-op tile. grid: B*32 = 256 blocks, 256 thr.
__global__ __launch_bounds__(256) void k_mid1(const float* __restrict__ S,
                                              const float* __restrict__ s,
                                              const float* __restrict__ phi_w,
                                              const float* __restrict__ phi_b,
                                              const float* __restrict__ gwT,
                                              const float* __restrict__ g_b,
                                              float* __restrict__ MT) {
  const int b = blockIdx.x >> 5, ot = blockIdx.x & 31;
  const int tid = threadIdx.x;
  __shared__ float pw[4][257], t2[4][257], sl[256], ps_s[4], pb_s[4], redw[4][4];
  sl[tid] = s[b * C_ + tid];
#pragma unroll
  for (int r = 0; r < 4; r++) pw[r][tid] = phi_w[(ot * 4 + r) * C_ + tid];
  if (tid < 4) pb_s[tid] = phi_b[ot * 4 + tid];
  __syncthreads();
  float acc4[4] = {};
  const float* Sbr = S + (size_t)b * C_ * C_;
#pragma unroll 4
  for (int cp = 0; cp < C_; cp++) {
    float sv = Sbr[(size_t)cp * C_ + tid];
#pragma unroll
    for (int r = 0; r < 4; r++) acc4[r] += pw[r][cp] * sv;
  }
  const int lane = tid & 63, w = tid >> 6;
#pragma unroll
  for (int r = 0; r < 4; r++) {
    float v = pw[r][tid] * sl[tid];
#pragma unroll
    for (int off = 1; off < 64; off <<= 1) v += __shfl_xor(v, off, 64);
    if (lane == 0) redw[w][r] = v;
  }
#pragma unroll
  for (int r = 0; r < 4; r++) t2[r][tid] = acc4[r] + pb_s[r] * sl[tid];
  __syncthreads();
  if (tid < 4) ps_s[tid] = redw[0][tid] + redw[1][tid] + redw[2][tid] + redw[3][tid];
  __syncthreads();
  const int o = tid & 127, half = tid >> 7;
  float m0 = 0.f, m1 = 0.f;
#pragma unroll 4
  for (int c = 0; c < C_; c++) {
    float gv = gwT[c * OC_ + o];
    m0 += t2[half * 2][c] * gv;
    m1 += t2[half * 2 + 1][c] * gv;
  }
  float gb = g_b[o];
  int r0 = half * 2;
  MT[((size_t)b * OC_ + o) * OC_ + ot * 4 + r0]     = m0 + (ps_s[r0] + (float)L_ * pb_s[r0]) * gb;
  MT[((size_t)b * OC_ + o) * OC_ + ot * 4 + r0 + 1] = m1 + (ps_s[r0 + 1] + (float)L_ * pb_s[r0 + 1]) * gb;
}

// U -> q -> Qb(bf16) -> qs,sum1 for a 4-c-row tile. grid: B*64 = 512 blocks, 256 thr.
__global__ __launch_bounds__(256) void k_mid2(const float* __restrict__ MT,
                                              const float* __restrict__ W_w,
                                              const float* __restrict__ theta_w,
                                              const float* __restrict__ theta_b,
                                              const float* __restrict__ W_b,
                                              const float* __restrict__ s,
                                              u16* __restrict__ Qb,
                                              float* __restrict__ qv,
                                              float* __restrict__ qs_g,
                                              float* __restrict__ sum1) {
  const int b = blockIdx.x >> 6, ct = blockIdx.x & 63;
  const int c0 = ct * 4;
  const int tid = threadIdx.x;
  __shared__ float ww[4][OC_], u_s[4][OC_ + 2], s_l[C_], q_s[4], redq[4][4];
  s_l[tid] = s[b * C_ + tid];
#pragma unroll
  for (int i = tid; i < 4 * OC_; i += 256)
    ww[i >> 7][i & 127] = W_w[(c0 + (i >> 7)) * OC_ + (i & 127)];
  __syncthreads();
  const int op = tid & 127, rh = tid >> 7;
  float ua0 = 0.f, ua1 = 0.f;
  const float* MTb = MT + (size_t)b * OC_ * OC_;
#pragma unroll 4
  for (int o = 0; o < OC_; o++) {
    float mv = MTb[(size_t)o * OC_ + op];
    ua0 += ww[rh * 2][o] * mv;
    ua1 += ww[rh * 2 + 1][o] * mv;
  }
  u_s[rh * 2][op] = ua0 * (1.f / (float)L_);
  u_s[rh * 2 + 1][op] = ua1 * (1.f / (float)L_);
  __syncthreads();
  {
    const int r = tid >> 6, lane = tid & 63;
    float v = u_s[r][lane] * theta_b[lane] + u_s[r][lane + 64] * theta_b[lane + 64];
#pragma unroll
    for (int off = 1; off < 64; off <<= 1) v += __shfl_xor(v, off, 64);
    if (lane == 0) {
      float qval = v + W_b[c0 + r];
      q_s[r] = qval;
      qv[b * C_ + c0 + r] = qval;
    }
  }
  float qa[4] = {};
#pragma unroll 2
  for (int o = 0; o < OC_; o++) {
    float tv = theta_w[(size_t)o * C_ + tid];
#pragma unroll
    for (int r = 0; r < 4; r++) qa[r] += u_s[r][o] * tv;
  }
#pragma unroll
  for (int r = 0; r < 4; r++)
    Qb[((size_t)b * C_ + c0 + r) * C_ + tid] = f2bf(qa[r]);
  const int lane = tid & 63, w = tid >> 6;
#pragma unroll
  for (int r = 0; r < 4; r++) {
    float v = qa[r] * s_l[tid];
#pragma unroll
    for (int off = 1; off < 64; off <<= 1) v += __shfl_xor(v, off, 64);
    if (lane == 0) redq[w][r] = v;
  }
  __syncthreads();
  if (tid < 4) {
    float qs = redq[0][tid] + redq[1][tid] + redq[2][tid] + redq[3][tid];
    qs_g[b * C_ + c0 + tid] = qs;
    sum1[b * C_ + c0 + tid] = qs + (float)L_ * q_s[tid];
  }
}

// e2 partials via MFMA, k-split x4. grid: (4 ks, 4 (chs*2+ct), B) = 128 blocks.
__global__ __launch_bounds__(256) void k_ystat(const u16* __restrict__ Qb,
                                               const u16* __restrict__ Sb,
                                               float* __restrict__ e2part) {
  const int b = blockIdx.z;
  const int chs = blockIdx.y >> 1, ct = blockIdx.y & 1;
  const int ks = blockIdx.x;
  __shared__ u16 lds[2 * 128 * 64];
  __shared__ float e2s[128][2];
  const int tid = threadIdx.x, lane = tid & 63;
  const int wid = tid >> 6, wr = wid >> 1, wc = wid & 1;
  const u16* Abase = Qb + ((size_t)b * C_ + ct * 128) * C_;
  const u16* Bbase = Sb + ((size_t)b * C_ + chs * 128) * C_;
  const int k0 = ks * 64;
  f32x4 acc[4][4] = {};
#pragma unroll
  for (int ch = 0; ch < 4; ch++) {
    int d = ch * 4096 + tid * 16;
    int row = d >> 7;
    int kb = (d & 127) ^ ((row & 7) << 4);
    gload_lds16(Abase + (size_t)row * C_ + k0 + (kb >> 1), (char*)lds + d);
    gload_lds16(Bbase + (size_t)row * C_ + k0 + (kb >> 1), (char*)lds + 16384 + d);
  }
  asm volatile("s_waitcnt vmcnt(0)" ::: "memory");
  __syncthreads();
#pragma unroll
  for (int kk = 0; kk < 2; kk++) {
    bf16x8 af[4], bfr[4];
#pragma unroll
    for (int m = 0; m < 4; m++) {
      int row = wr * 64 + m * 16 + (lane & 15);
      int kb = ((kk << 6) + ((lane >> 4) << 4)) ^ ((row & 7) << 4);
      af[m] = *(const bf16x8*)((const char*)lds + row * 128 + kb);
    }
#pragma unroll
    for (int n = 0; n < 4; n++) {
      int row = wc * 64 + n * 16 + (lane & 15);
      int kb = ((kk << 6) + ((lane >> 4) << 4)) ^ ((row & 7) << 4);
      bfr[n] = *(const bf16x8*)((const char*)lds + 16384 + row * 128 + kb);
    }
#pragma unroll
    for (int m = 0; m < 4; m++)
#pragma unroll
      for (int n = 0; n < 4; n++)
        acc[m][n] = __builtin_amdgcn_mfma_f32_16x16x32_bf16(af[m], bfr[n], acc[m][n], 0, 0, 0);
  }
  float e2a[4][4];
#pragma unroll
  for (int m = 0; m < 4; m++)
#pragma unroll
    for (int r = 0; r < 4; r++) e2a[m][r] = 0.f;
#pragma unroll
  for (int m = 0; m < 4; m++)
#pragma unroll
    for (int n = 0; n < 4; n++) {
      int ch = chs * 128 + wc * 64 + n * 16 + (lane & 15);
#pragma unroll
      for (int r = 0; r < 4; r++) {
        int c_loc = wr * 64 + m * 16 + ((lane >> 4) << 2) + r;
        float q2 = bf2f(Qb[((size_t)b * C_ + ct * 128 + c_loc) * C_ + ch]);
        e2a[m][r] += acc[m][n][r] * q2;
      }
    }
#pragma unroll
  for (int m = 0; m < 4; m++)
#pragma unroll
    for (int r = 0; r < 4; r++) {
      float v = e2a[m][r];
      v += __shfl_xor(v, 1, 64);
      v += __shfl_xor(v, 2, 64);
      v += __shfl_xor(v, 4, 64);
      v += __shfl_xor(v, 8, 64);
      if ((lane & 15) == 0) {
        int c_loc = wr * 64 + m * 16 + ((lane >> 4) << 2) + r;
        e2s[c_loc][wc] = v;
      }
    }
  __syncthreads();
  if (tid < 128)
    e2part[(((size_t)chs * 4 + ks) * B_ + b) * C_ + ct * 128 + tid] =
        e2s[tid][0] + e2s[tid][1];
}

// BN finalize (prologue) + out = (gsc*Qb + I) @ Xb + qp.  A reg-staged w/ gsc+I,
// B gload_lds, 2-phase dbuf. grid: (L/128, C/128, B) = 512 blocks, 256 thr.
__global__ __launch_bounds__(256) void k_out(const u16* __restrict__ Qb,
                                             const float* __restrict__ qv,
                                             const float* __restrict__ qs_g,
                                             const float* __restrict__ sum1,
                                             const float* __restrict__ e2part,
                                             const float* __restrict__ gamma,
                                             const float* __restrict__ beta,
                                             const u16* __restrict__ XbT,
                                             float* __restrict__ out) {
  const int b = blockIdx.z, ct = blockIdx.y, lt = blockIdx.x;
  __shared__ u16 Albs[2][128 * 64];
  __shared__ u16 Blbs[2][128 * 64];
  __shared__ float gsc_s[128], qp_s[128];
  const int tid = threadIdx.x, lane = tid & 63;
  const int wid = tid >> 6, wr = wid >> 1, wc = wid & 1;
  if (tid < 128) {
    int c = ct * 128 + tid;
    float m_ = 0.f, e_ = 0.f;
#pragma unroll
    for (int bb = 0; bb < B_; bb++) {
      m_ += sum1[bb * C_ + c];
      float e2 = 0.f;
#pragma unroll
      for (int sl = 0; sl < 8; sl++) e2 += e2part[((size_t)sl * B_ + bb) * C_ + c];
      float qq = qv[bb * C_ + c], qs = qs_g[bb * C_ + c];
      e_ += e2 + 2.f * qq * qs + (float)L_ * qq * qq;
    }
    const float inv_n = 1.f / (float)(B_ * L_);
    m_ *= inv_n;
    e_ *= inv_n;
    float var = e_ - m_ * m_;
    float g = gamma[c] * rsqrtf(var + EPS_);
    gsc_s[tid] = g;
    qp_s[tid] = g * (qv[b * C_ + c] - m_) + beta[c];
  }
  __syncthreads();
  const u16* Bbase = XbT + ((size_t)b * L_ + lt * 128) * C_;
  f32x4 acc[4][4] = {};
  u16x4 regs[8];
  const int jr = (tid & 15) * 4;
  const int rb = tid >> 4;
  auto LOADA = [&](int k0) {
#pragma unroll
    for (int pass = 0; pass < 8; pass++) {
      int row = pass * 16 + rb;
      regs[pass] = *(const u16x4*)(Qb + ((size_t)b * C_ + ct * 128 + row) * C_ + k0 + jr);
    }
  };
  auto WRITEA = [&](int buf, int k0) {
#pragma unroll
    for (int pass = 0; pass < 8; pass++) {
      int row = pass * 16 + rb;
      float g = gsc_s[row];
      int c = ct * 128 + row;
      u16x4 h;
#pragma unroll
      for (int i = 0; i < 4; i++) {
        float a = g * bf2f(regs[pass][i]);
        if (k0 + jr + i == c) a += 1.f;
        h[i] = f2bf(a);
      }
      int byte = (jr * 2) ^ ((row & 7) << 4);
      *(u16x4*)((char*)Albs[buf] + row * 128 + byte) = h;
    }
  };
  auto STAGEB = [&](int buf, int k0) {
#pragma unroll
    for (int ch = 0; ch < 4; ch++) {
      int d = ch * 4096 + tid * 16;
      int row = d >> 7;
      int kb = (d & 127) ^ ((row & 7) << 4);
      gload_lds16(Bbase + (size_t)row * C_ + k0 + (kb >> 1), (char*)Blbs[buf] + d);
    }
  };
  LOADA(0);
  STAGEB(0, 0);
  asm volatile("s_waitcnt vmcnt(0)" ::: "memory");
  WRITEA(0, 0);
  __syncthreads();
  int cur = 0;
  for (int k0 = 0; k0 < C_; k0 += 64) {
    bool hasNext = (k0 + 64 < C_);
    if (hasNext) {
      STAGEB(cur ^ 1, k0 + 64);
      LOADA(k0 + 64);
    }
#pragma unroll
    for (int kk = 0; kk < 2; kk++) {
      bf16x8 af[4], bfr[4];
#pragma unroll
      for (int m = 0; m < 4; m++) {
        int row = wr * 64 + m * 16 + (lane & 15);
        int kb = ((kk << 6) + ((lane >> 4) << 4)) ^ ((row & 7) << 4);
        af[m] = *(const bf16x8*)((const char*)Albs[cur] + row * 128 + kb);
      }
#pragma unroll
      for (int n = 0; n < 4; n++) {
        int row = wc * 64 + n * 16 + (lane & 15);
        int kb = ((kk << 6) + ((lane >> 4) << 4)) ^ ((row & 7) << 4);
        bfr[n] = *(const bf16x8*)((const char*)Blbs[cur] + row * 128 + kb);
      }
#pragma unroll
      for (int m = 0; m < 4; m++)
#pragma unroll
        for (int n = 0; n < 4; n++)
          acc[m][n] = __builtin_amdgcn_mfma_f32_16x16x32_bf16(af[m], bfr[n], acc[m][n], 0, 0, 0);
    }
    if (hasNext) {
      asm volatile("s_waitcnt vmcnt(0)" ::: "memory");
      WRITEA(cur ^ 1, k0 + 64);
    }
    __syncthreads();
    cur ^= 1;
  }
#pragma unroll
  for (int m = 0; m < 4; m++)
#pragma unroll
    for (int n = 0; n < 4; n++) {
      int cl = wr * 64 + m * 16 + ((lane >> 4) << 2);
      int c = ct * 128 + cl;
      int l = lt * 128 + wc * 64 + n * 16 + (lane & 15);
#pragma unroll
      for (int r = 0; r < 4; r++) {
        size_t gi = ((size_t)b * C_ + c + r) * L_ + l;
        out[gi] = acc[m][n][r] + qp_s[cl + r];
      }
    }
}

extern "C" void kernel_launch(void* const* d_in, const int* in_sizes, int n_in,
                              void* d_out, int out_size, void* d_ws, size_t ws_size,
                              hipStream_t stream) {
  const float* x       = (const float*)d_in[0];
  const float* g_w     = (const float*)d_in[1];
  const float* g_b     = (const float*)d_in[2];
  const float* theta_w = (const float*)d_in[3];
  const float* theta_b = (const float*)d_in[4];
  const float* phi_w   = (const float*)d_in[5];
  const float* phi_b   = (const float*)d_in[6];
  const float* W_w     = (const float*)d_in[7];
  const float* W_b     = (const float*)d_in[8];
  const float* gamma   = (const float*)d_in[9];
  const float* beta    = (const float*)d_in[10];
  float* out = (float*)d_out;

  float* ws = (float*)d_ws;
  size_t off = 0;
  float* Spart    = ws + off; off += (size_t)SPLITK * B_ * C_ * C_;
  float* S        = ws + off; off += (size_t)B_ * C_ * C_;
  float* spartial = ws + off; off += (size_t)B_ * C_ * 64;
  float* s_       = ws + off; off += B_ * C_;
  float* gwT      = ws + off; off += C_ * OC_;
  float* MT       = ws + off; off += (size_t)B_ * OC_ * OC_;
  float* qv       = ws + off; off += B_ * C_;
  float* qs_g     = ws + off; off += B_ * C_;
  float* sum1     = ws + off; off += B_ * C_;
  float* e2part   = ws + off; off += 8 * B_ * C_;
  u16* Sb  = (u16*)(ws + off); off += (size_t)B_ * C_ * C_ / 2;
  u16* Qb  = (u16*)(ws + off); off += (size_t)B_ * C_ * C_ / 2;
  u16* Xb  = (u16*)(ws + off); off += (size_t)B_ * C_ * L_ / 2;
  u16* XbT = (u16*)(ws + off); off += (size_t)B_ * C_ * L_ / 2;

  k_cvt<<<dim3(L_ / 64, C_ / 64, B_), 256, 0, stream>>>(x, Xb, XbT, spartial);
  k_xxt<<<dim3(16, SPLITK, B_), 256, 0, stream>>>(Xb, Spart);
  k_sreduce<<<(B_ * C_ * C_) / 256 + (B_ * C_) / 256 + 16, 256, 0, stream>>>(
      Spart, spartial, g_w, S, Sb, s_, gwT);
  k_mid1<<<B_ * 32, 256, 0, stream>>>(S, s_, phi_w, phi_b, gwT, g_b, MT);
  k_mid2<<<B_ * 64, 256, 0, stream>>>(MT, W_w, theta_w, theta_b, W_b, s_,
                                      Qb, qv, qs_g, sum1);
  k_ystat<<<dim3(4, 4, B_), 256, 0, stream>>>(Qb, Sb, e2part);
  k_out<<<dim3(L_ / 128, C_ / 128, B_), 256, 0, stream>>>(
      Qb, qv, qs_g, sum1, e2part, gamma, beta, XbT, out);
}